// Round 1
// baseline (287.211 us; speedup 1.0000x reference)
//
#include <hip/hip_runtime.h>

typedef unsigned short u16;
typedef __bf16 bf16x8 __attribute__((ext_vector_type(8)));
typedef float f32x4 __attribute__((ext_vector_type(4)));

#define Bq 4
#define Dq 768
#define Lq 4096
#define Mq (Lq * Bq)   // 16384

__device__ __forceinline__ u16 f2bf(float f) {
    unsigned int u = __builtin_bit_cast(unsigned int, f);
    u += 0x7fffu + ((u >> 16) & 1u);   // RNE
    return (u16)(u >> 16);
}

__device__ __forceinline__ void async16(const void* g, void* l) {
    __builtin_amdgcn_global_load_lds(
        (const __attribute__((address_space(1))) unsigned int*)(unsigned long long)g,
        (__attribute__((address_space(3))) unsigned int*)(unsigned int)(unsigned long long)l,
        16, 0, 0);
}

// ---- prep: fp32 weights -> bf16, zero the 4 pad rows of Vpad/Gpad ----
__global__ __launch_bounds__(256) void prep_kernel(
    const float* __restrict__ Wih, const float* __restrict__ Whh,
    u16* __restrict__ Wihb, u16* __restrict__ Whhb,
    u16* __restrict__ Vpad, u16* __restrict__ Gpad) {
    int i = blockIdx.x * 256 + threadIdx.x;
    if (i < Dq * Dq) {
        Wihb[i] = f2bf(Wih[i]);
        Whhb[i] = f2bf(Whh[i]);
    }
    if (i < Bq * Dq) { Vpad[i] = 0; Gpad[i] = 0; }
}

// ---- transpose x [B,D,L] fp32 -> Xt [(l*B+b), d] bf16 ----
__global__ __launch_bounds__(256) void transpose_kernel(
    const float* __restrict__ x, u16* __restrict__ Xt) {
    __shared__ u16 tile[64][66];   // +2 pad: conflict-free transposed reads
    int b = blockIdx.z, d0 = blockIdx.y * 64, l0 = blockIdx.x * 64;
    int tx = threadIdx.x & 63, ty = threadIdx.x >> 6;
    const float* xp = x + ((size_t)b * Dq + d0) * Lq + l0;
#pragma unroll
    for (int i = 0; i < 16; ++i) {
        int r = i * 4 + ty;
        tile[r][tx] = f2bf(xp[(size_t)r * Lq + tx]);   // lanes along l: coalesced
    }
    __syncthreads();
    u16* xt = Xt + ((size_t)l0 * Bq + b) * Dq + d0;
#pragma unroll
    for (int i = 0; i < 16; ++i) {
        int c = i * 4 + ty;
        xt[(size_t)c * Bq * Dq + tx] = tile[tx][c];    // lanes along d: coalesced
    }
}

// ---- GEMM: C[m,n] = sum_k A[m,k]*W[n,k]; M=16384, N=K=768 ----
// MODE 1: U = acc + b_ih (store fp32); Vpad = bf16(relu(U + b_hh)) at +4 rows
// MODE 2: Gpad = bf16(relu(U + b_hh + acc)) at +4 rows   (A = Vpad, shifted via pad)
// MODE 3: E = relu(U + b_hh + acc), stored transposed to [B,D,L] fp32 via LDS
template <int MODE>
__global__ __launch_bounds__(256) void gemm_kernel(
    const u16* __restrict__ A, const u16* __restrict__ W,
    float* __restrict__ U, u16* __restrict__ OutBf,
    float* __restrict__ Eout,
    const float* __restrict__ bih, const float* __restrict__ bhh) {
    extern __shared__ __align__(16) char smem[];
    u16* As = (u16*)smem;               // [128][32] bf16
    u16* Bs = (u16*)(smem + 8192);      // [128][32] bf16
    float* ep = (float*)(smem + 16384); // MODE 3: [4 waves][64][17]

    int tid = threadIdx.x;
    int wave = tid >> 6, lane = tid & 63;
    int wr = wave >> 1, wc = wave & 1;
    int m0 = blockIdx.y * 128, n0 = blockIdx.x * 128;
    int lr = lane & 15, lq = lane >> 4;

    // staging addresses: wave w stages rows [w*32, w*32+32) of each tile,
    // lane -> (row = lane/4, kq = lane%4): LDS offset == lane*16B (HW requirement)
    int srow = wave * 32 + (lane >> 2);
    int scol = (lane & 3) * 8;
    const u16* ga = A + (size_t)(m0 + srow) * Dq + scol;
    const u16* gb = W + (size_t)(n0 + srow) * Dq + scol;
    u16* laA0 = As + (wave * 32) * 32;
    u16* laA1 = As + (wave * 32 + 16) * 32;
    u16* laB0 = Bs + (wave * 32) * 32;
    u16* laB1 = Bs + (wave * 32 + 16) * 32;

    f32x4 acc[4][4];
#pragma unroll
    for (int i = 0; i < 4; ++i)
#pragma unroll
        for (int j = 0; j < 4; ++j) acc[i][j] = f32x4{0.f, 0.f, 0.f, 0.f};

    for (int k0 = 0; k0 < Dq; k0 += 32) {
        async16(ga, laA0);
        async16(ga + 16 * Dq, laA1);
        async16(gb, laB0);
        async16(gb + 16 * Dq, laB1);
        ga += 32; gb += 32;
        __syncthreads();   // drains vmcnt (global_load_lds) + lds

        bf16x8 af[4], bfr[4];
#pragma unroll
        for (int mt = 0; mt < 4; ++mt)
            af[mt] = *(const bf16x8*)(As + (wr * 64 + mt * 16 + lr) * 32 + lq * 8);
#pragma unroll
        for (int nt = 0; nt < 4; ++nt)
            bfr[nt] = *(const bf16x8*)(Bs + (wc * 64 + nt * 16 + lr) * 32 + lq * 8);
#pragma unroll
        for (int mt = 0; mt < 4; ++mt)
#pragma unroll
            for (int nt = 0; nt < 4; ++nt)
                acc[mt][nt] = __builtin_amdgcn_mfma_f32_16x16x32_bf16(
                    af[mt], bfr[nt], acc[mt][nt], 0, 0, 0);
        __syncthreads();
    }

    // ---- epilogue ----  C/D layout: col = lane&15, row = (lane>>4)*4 + r
    if constexpr (MODE == 1) {
#pragma unroll
        for (int nt = 0; nt < 4; ++nt) {
            int gn = n0 + wc * 64 + nt * 16 + lr;
            float bi = bih[gn], bh = bhh[gn];
#pragma unroll
            for (int mt = 0; mt < 4; ++mt) {
                int gm = m0 + wr * 64 + mt * 16 + lq * 4;
                f32x4 v = acc[mt][nt];
#pragma unroll
                for (int r = 0; r < 4; ++r) {
                    float u = v[r] + bi;
                    U[(size_t)(gm + r) * Dq + gn] = u;
                    OutBf[(size_t)(gm + r + Bq) * Dq + gn] = f2bf(fmaxf(u + bh, 0.f));
                }
            }
        }
    } else if constexpr (MODE == 2) {
#pragma unroll
        for (int nt = 0; nt < 4; ++nt) {
            int gn = n0 + wc * 64 + nt * 16 + lr;
            float bh = bhh[gn];
#pragma unroll
            for (int mt = 0; mt < 4; ++mt) {
                int gm = m0 + wr * 64 + mt * 16 + lq * 4;
                f32x4 v = acc[mt][nt];
#pragma unroll
                for (int r = 0; r < 4; ++r) {
                    float g = fmaxf(U[(size_t)(gm + r) * Dq + gn] + bh + v[r], 0.f);
                    OutBf[(size_t)(gm + r + Bq) * Dq + gn] = f2bf(g);
                }
            }
        }
    } else {
        // MODE 3: transpose through LDS so [B,D,L] writes are contiguous in l
        float* epw = ep + wave * (64 * 17);
        int l0w = (m0 >> 2) + wr * 16;   // wave covers 16 l values, 4 b values
#pragma unroll
        for (int nt = 0; nt < 4; ++nt) {
            int gn = n0 + wc * 64 + nt * 16 + lr;
            float bh = bhh[gn];
#pragma unroll
            for (int mt = 0; mt < 4; ++mt) {
                int lmb = mt * 16 + lq * 4;
                int gm = m0 + wr * 64 + lmb;
                f32x4 v = acc[mt][nt];
#pragma unroll
                for (int r = 0; r < 4; ++r) {
                    float e = fmaxf(U[(size_t)(gm + r) * Dq + gn] + bh + v[r], 0.f);
                    epw[(lmb + r) * 17 + lr] = e;
                }
            }
            __syncthreads();
            int bb = lane >> 4, cc = lane & 15;
            int gnc = n0 + wc * 64 + nt * 16 + cc;
            float vals[16];
#pragma unroll
            for (int ll = 0; ll < 16; ++ll)
                vals[ll] = epw[(ll * 4 + bb) * 17 + cc];
            float* dst = Eout + (size_t)bb * (Dq * Lq) + (size_t)gnc * Lq + l0w;
#pragma unroll
            for (int s = 0; s < 4; ++s) {
                f32x4 w4 = {vals[s * 4], vals[s * 4 + 1], vals[s * 4 + 2], vals[s * 4 + 3]};
                *(f32x4*)(dst + s * 4) = w4;
            }
            __syncthreads();
        }
    }
}

// ---- fused residual + LayerNorm over L (contiguous rows of 4096) ----
__global__ __launch_bounds__(256) void ln_kernel(
    const float* __restrict__ E, const float* __restrict__ x,
    const float* __restrict__ gamma, const float* __restrict__ beta,
    float* __restrict__ out) {
    __shared__ float red[2][4];
    size_t row = blockIdx.x;
    const float* e = E + row * Lq;
    const float* xr = x + row * Lq;
    float* o = out + row * Lq;
    int t = threadIdx.x;
    float z[16];
    float s = 0.f, sq = 0.f;
#pragma unroll
    for (int i = 0; i < 4; ++i) {
        int idx = (i * 256 + t) * 4;
        f32x4 ev = *(const f32x4*)(e + idx);
        f32x4 xv = *(const f32x4*)(xr + idx);
#pragma unroll
        for (int j = 0; j < 4; ++j) {
            float zz = ev[j] + xv[j];
            z[i * 4 + j] = zz;
            s += zz;
            sq += zz * zz;
        }
    }
#pragma unroll
    for (int off = 32; off > 0; off >>= 1) {
        s += __shfl_down(s, off);
        sq += __shfl_down(sq, off);
    }
    int wave = t >> 6, lane = t & 63;
    if (lane == 0) { red[0][wave] = s; red[1][wave] = sq; }
    __syncthreads();
    s = red[0][0] + red[0][1] + red[0][2] + red[0][3];
    sq = red[1][0] + red[1][1] + red[1][2] + red[1][3];
    float mean = s * (1.f / Lq);
    float var = sq * (1.f / Lq) - mean * mean;
    float rstd = rsqrtf(var + 1e-12f);
#pragma unroll
    for (int i = 0; i < 4; ++i) {
        int idx = (i * 256 + t) * 4;
        f32x4 gv = *(const f32x4*)(gamma + idx);
        f32x4 bv = *(const f32x4*)(beta + idx);
        f32x4 ov;
#pragma unroll
        for (int j = 0; j < 4; ++j)
            ov[j] = (z[i * 4 + j] - mean) * rstd * gv[j] + bv[j];
        *(f32x4*)(o + idx) = ov;
    }
}

extern "C" void kernel_launch(void* const* d_in, const int* in_sizes, int n_in,
                              void* d_out, int out_size, void* d_ws, size_t ws_size,
                              hipStream_t stream) {
    const float* x     = (const float*)d_in[0];
    const float* Wih   = (const float*)d_in[1];
    const float* Whh   = (const float*)d_in[2];
    const float* bih   = (const float*)d_in[3];
    const float* bhh   = (const float*)d_in[4];
    const float* gamma = (const float*)d_in[5];
    const float* beta  = (const float*)d_in[6];
    float* out = (float*)d_out;

    char* ws = (char*)d_ws;
    u16* Xt    = (u16*)ws;              ws += (size_t)Mq * Dq * 2;        // 25.2 MB
    u16* Wihb  = (u16*)ws;              ws += (size_t)Dq * Dq * 2;
    u16* Whhb  = (u16*)ws;              ws += (size_t)Dq * Dq * 2;
    float* U   = (float*)ws;            ws += (size_t)Mq * Dq * 4;        // 50.3 MB
    u16* Vpad  = (u16*)ws;              ws += (size_t)(Mq + Bq) * Dq * 2; // 25.2 MB
    u16* Gpad  = (u16*)ws;              ws += (size_t)(Mq + Bq) * Dq * 2; // 25.2 MB
    float* Eout = (float*)ws;           ws += (size_t)Mq * Dq * 4;        // 50.3 MB

    prep_kernel<<<dim3((Dq * Dq + 255) / 256), 256, 0, stream>>>(
        Wih, Whh, Wihb, Whhb, Vpad, Gpad);
    transpose_kernel<<<dim3(Lq / 64, Dq / 64, Bq), 256, 0, stream>>>(x, Xt);

    dim3 ggrid(Dq / 128, Mq / 128);   // (6, 128)
    gemm_kernel<1><<<ggrid, 256, 16384, stream>>>(Xt,   Wihb, U, Vpad, nullptr, bih, bhh);
    gemm_kernel<2><<<ggrid, 256, 16384, stream>>>(Vpad, Whhb, U, Gpad, nullptr, bih, bhh);
    gemm_kernel<3><<<ggrid, 256, 33792, stream>>>(Gpad, Whhb, U, nullptr, Eout, bih, bhh);

    ln_kernel<<<dim3(Bq * Dq), 256, 0, stream>>>(Eout, x, gamma, beta, out);
}

// Round 2
// 275.132 us; speedup vs baseline: 1.0439x; 1.0439x over previous
//
#include <hip/hip_runtime.h>

typedef unsigned short u16;
typedef __bf16 bf16x8 __attribute__((ext_vector_type(8)));
typedef float f32x4 __attribute__((ext_vector_type(4)));
typedef unsigned short u16x8 __attribute__((ext_vector_type(8)));

#define Bq 4
#define Dq 768
#define Lq 4096
#define Mq (Lq * Bq)   // 16384

__device__ __forceinline__ u16 f2bf(float f) {
    unsigned int u = __builtin_bit_cast(unsigned int, f);
    u += 0x7fffu + ((u >> 16) & 1u);   // RNE
    return (u16)(u >> 16);
}

__device__ __forceinline__ float bf2f(u16 h) {
    return __builtin_bit_cast(float, (unsigned int)h << 16);
}

__device__ __forceinline__ void async16(const void* g, void* l) {
    __builtin_amdgcn_global_load_lds(
        (const __attribute__((address_space(1))) unsigned int*)(unsigned long long)g,
        (__attribute__((address_space(3))) unsigned int*)(unsigned int)(unsigned long long)l,
        16, 0, 0);
}

// ---- prep: fp32 weights -> bf16, zero the 4 pad rows of Vpad/Gpad ----
__global__ __launch_bounds__(256) void prep_kernel(
    const float* __restrict__ Wih, const float* __restrict__ Whh,
    u16* __restrict__ Wihb, u16* __restrict__ Whhb,
    u16* __restrict__ Vpad, u16* __restrict__ Gpad) {
    int i = blockIdx.x * 256 + threadIdx.x;
    if (i < Dq * Dq) {
        Wihb[i] = f2bf(Wih[i]);
        Whhb[i] = f2bf(Whh[i]);
    }
    if (i < Bq * Dq) { Vpad[i] = 0; Gpad[i] = 0; }
}

// ---- transpose x [B,D,L] fp32 -> Xt [(l*B+b), d] bf16 ----
__global__ __launch_bounds__(256) void transpose_kernel(
    const float* __restrict__ x, u16* __restrict__ Xt) {
    __shared__ u16 tile[64][66];
    int b = blockIdx.z, d0 = blockIdx.y * 64, l0 = blockIdx.x * 64;
    int tx = threadIdx.x & 63, ty = threadIdx.x >> 6;
    const float* xp = x + ((size_t)b * Dq + d0) * Lq + l0;
#pragma unroll
    for (int i = 0; i < 16; ++i) {
        int r = i * 4 + ty;
        tile[r][tx] = f2bf(xp[(size_t)r * Lq + tx]);
    }
    __syncthreads();
    u16* xt = Xt + ((size_t)l0 * Bq + b) * Dq + d0;
#pragma unroll
    for (int i = 0; i < 16; ++i) {
        int c = i * 4 + ty;
        xt[(size_t)c * Bq * Dq + tx] = tile[tx][c];
    }
}

// ---- GEMM: C[m,n] = sum_seg sum_k Aseg[m,k]*Wseg[n,k], then relu(+bias) ----
// NSEG=1: out = relu(A0@W0^T + b)                (pass A: V)
// NSEG=2: out = relu(A0@W0^T + A1@W1^T + b)      (pass B: G, pass C: E)
// MODE 0: write bf16 to Out at rows +4 (Vpad/Gpad shift-by-one-l via pad)
// MODE 1: write bf16 transposed to Out as [B,D,L] (Eout) via LDS transpose
// BK=64 per iteration, staged as two 32-col sub-tiles (keeps 32-col LDS rows).
template <int NSEG, int MODE>
__global__ __launch_bounds__(256) void gemm_kernel(
    const u16* __restrict__ A0, const u16* __restrict__ W0,
    const u16* __restrict__ A1, const u16* __restrict__ W1,
    u16* __restrict__ Out,
    const float* __restrict__ bih, const float* __restrict__ bhh) {
    __shared__ __align__(16) char smem[32768];
    u16* As0 = (u16*)smem;          // [128][32] bf16, k 0..31 of the 64-chunk
    u16* As1 = As0 + 4096;          // [128][32],       k 32..63
    u16* Bs0 = As0 + 8192;
    u16* Bs1 = As0 + 12288;

    int tid = threadIdx.x;
    int wave = tid >> 6, lane = tid & 63;
    int wr = wave >> 1, wc = wave & 1;
    int m0 = blockIdx.x * 128, n0 = blockIdx.y * 128;
    int lr = lane & 15, lq = lane >> 4;

    // staging: wave w stages rows [w*32, w*32+32). Per async16: 64 lanes cover
    // 16 rows x 32 cols; lane -> (row = lane>>2, colseg = lane&3).
    int srow = wave * 32 + (lane >> 2);
    int scol = (lane & 3) * 8;
    u16* lA0a = As0 + (wave * 32) * 32;
    u16* lA0b = As0 + (wave * 32 + 16) * 32;
    u16* lA1a = As1 + (wave * 32) * 32;
    u16* lA1b = As1 + (wave * 32 + 16) * 32;
    u16* lB0a = Bs0 + (wave * 32) * 32;
    u16* lB0b = Bs0 + (wave * 32 + 16) * 32;
    u16* lB1a = Bs1 + (wave * 32) * 32;
    u16* lB1b = Bs1 + (wave * 32 + 16) * 32;

    f32x4 acc[4][4];
#pragma unroll
    for (int i = 0; i < 4; ++i)
#pragma unroll
        for (int j = 0; j < 4; ++j) acc[i][j] = f32x4{0.f, 0.f, 0.f, 0.f};

#pragma unroll
    for (int seg = 0; seg < NSEG; ++seg) {
        const u16* Ab = (seg == 0) ? A0 : A1;
        const u16* Wb = (seg == 0) ? W0 : W1;
        const u16* ga = Ab + (size_t)(m0 + srow) * Dq + scol;
        const u16* gb = Wb + (size_t)(n0 + srow) * Dq + scol;

        for (int k0 = 0; k0 < Dq; k0 += 64) {
            async16(ga,               lA0a);
            async16(ga + 16 * Dq,     lA0b);
            async16(ga + 32,          lA1a);
            async16(ga + 16 * Dq + 32, lA1b);
            async16(gb,               lB0a);
            async16(gb + 16 * Dq,     lB0b);
            async16(gb + 32,          lB1a);
            async16(gb + 16 * Dq + 32, lB1b);
            ga += 64; gb += 64;
            __syncthreads();

#pragma unroll
            for (int s = 0; s < 2; ++s) {
                const u16* Asub = s ? As1 : As0;
                const u16* Bsub = s ? Bs1 : Bs0;
                bf16x8 af[4], bfr[4];
#pragma unroll
                for (int mt = 0; mt < 4; ++mt)
                    af[mt] = *(const bf16x8*)(Asub + (wr * 64 + mt * 16 + lr) * 32 + lq * 8);
#pragma unroll
                for (int nt = 0; nt < 4; ++nt)
                    bfr[nt] = *(const bf16x8*)(Bsub + (wc * 64 + nt * 16 + lr) * 32 + lq * 8);
#pragma unroll
                for (int mt = 0; mt < 4; ++mt)
#pragma unroll
                    for (int nt = 0; nt < 4; ++nt)
                        acc[mt][nt] = __builtin_amdgcn_mfma_f32_16x16x32_bf16(
                            af[mt], bfr[nt], acc[mt][nt], 0, 0, 0);
            }
            __syncthreads();
        }
    }

    // ---- epilogue ----  C/D layout: col = lane&15, row = (lane>>4)*4 + r
    if constexpr (MODE == 0) {
#pragma unroll
        for (int nt = 0; nt < 4; ++nt) {
            int gn = n0 + wc * 64 + nt * 16 + lr;
            float bsum = bih[gn] + bhh[gn];
#pragma unroll
            for (int mt = 0; mt < 4; ++mt) {
                int gm = m0 + wr * 64 + mt * 16 + lq * 4;
                f32x4 v = acc[mt][nt];
#pragma unroll
                for (int r = 0; r < 4; ++r)
                    Out[(size_t)(gm + r + Bq) * Dq + gn] = f2bf(fmaxf(v[r] + bsum, 0.f));
            }
        }
    } else {
        // transpose through LDS so [B,D,L] writes are contiguous in l
        float* ep = (float*)smem;            // safe: last K-iter ended in barrier
        float* epw = ep + wave * (64 * 17);
        int l0w = (m0 >> 2) + wr * 16;       // wave covers 16 l values, 4 b values
#pragma unroll
        for (int nt = 0; nt < 4; ++nt) {
            int gn = n0 + wc * 64 + nt * 16 + lr;
            float bsum = bih[gn] + bhh[gn];
#pragma unroll
            for (int mt = 0; mt < 4; ++mt) {
                int lmb = mt * 16 + lq * 4;
                f32x4 v = acc[mt][nt];
#pragma unroll
                for (int r = 0; r < 4; ++r)
                    epw[(lmb + r) * 17 + lr] = fmaxf(v[r] + bsum, 0.f);
            }
            __syncthreads();
            int bb = lane >> 4, cc = lane & 15;
            int gnc = n0 + wc * 64 + nt * 16 + cc;
            float vals[16];
#pragma unroll
            for (int ll = 0; ll < 16; ++ll)
                vals[ll] = epw[(ll * 4 + bb) * 17 + cc];
            u16* dst = Out + (size_t)bb * (Dq * Lq) + (size_t)gnc * Lq + l0w;
            u16x8 h0, h1;
#pragma unroll
            for (int j = 0; j < 8; ++j) { h0[j] = f2bf(vals[j]); h1[j] = f2bf(vals[8 + j]); }
            *(u16x8*)dst = h0;
            *(u16x8*)(dst + 8) = h1;
            __syncthreads();
        }
    }
}

// ---- fused residual + LayerNorm over L (E is bf16 [B,D,L]) ----
__global__ __launch_bounds__(256) void ln_kernel(
    const u16* __restrict__ E, const float* __restrict__ x,
    const float* __restrict__ gamma, const float* __restrict__ beta,
    float* __restrict__ out) {
    __shared__ float red[2][4];
    size_t row = blockIdx.x;
    const u16x8* e8 = (const u16x8*)(E + row * Lq);
    const float* xr = x + row * Lq;
    float* o = out + row * Lq;
    int t = threadIdx.x;
    float z[16];
    float s = 0.f, sq = 0.f;
#pragma unroll
    for (int i = 0; i < 2; ++i) {
        int c = i * 256 + t;                  // 8-elem chunk index
        u16x8 ev = e8[c];
        f32x4 xv0 = *(const f32x4*)(xr + c * 8);
        f32x4 xv1 = *(const f32x4*)(xr + c * 8 + 4);
#pragma unroll
        for (int j = 0; j < 4; ++j) {
            float z0 = bf2f(ev[j]) + xv0[j];
            float z1 = bf2f(ev[4 + j]) + xv1[j];
            z[i * 8 + j] = z0;
            z[i * 8 + 4 + j] = z1;
            s += z0 + z1;
            sq += z0 * z0 + z1 * z1;
        }
    }
#pragma unroll
    for (int off = 32; off > 0; off >>= 1) {
        s += __shfl_down(s, off);
        sq += __shfl_down(sq, off);
    }
    int wave = t >> 6, lane = t & 63;
    if (lane == 0) { red[0][wave] = s; red[1][wave] = sq; }
    __syncthreads();
    s = red[0][0] + red[0][1] + red[0][2] + red[0][3];
    sq = red[1][0] + red[1][1] + red[1][2] + red[1][3];
    float mean = s * (1.f / Lq);
    float var = sq * (1.f / Lq) - mean * mean;
    float rstd = rsqrtf(var + 1e-12f);
#pragma unroll
    for (int i = 0; i < 2; ++i) {
        int c = i * 256 + t;
#pragma unroll
        for (int h = 0; h < 2; ++h) {
            int idx = c * 8 + h * 4;
            f32x4 gv = *(const f32x4*)(gamma + idx);
            f32x4 bv = *(const f32x4*)(beta + idx);
            f32x4 ov;
#pragma unroll
            for (int j = 0; j < 4; ++j)
                ov[j] = (z[i * 8 + h * 4 + j] - mean) * rstd * gv[j] + bv[j];
            *(f32x4*)(o + idx) = ov;
        }
    }
}

extern "C" void kernel_launch(void* const* d_in, const int* in_sizes, int n_in,
                              void* d_out, int out_size, void* d_ws, size_t ws_size,
                              hipStream_t stream) {
    const float* x     = (const float*)d_in[0];
    const float* Wih   = (const float*)d_in[1];
    const float* Whh   = (const float*)d_in[2];
    const float* bih   = (const float*)d_in[3];
    const float* bhh   = (const float*)d_in[4];
    const float* gamma = (const float*)d_in[5];
    const float* beta  = (const float*)d_in[6];
    float* out = (float*)d_out;

    char* ws = (char*)d_ws;
    u16* Xt    = (u16*)ws;   ws += (size_t)Mq * Dq * 2;          // 25.2 MB
    u16* Wihb  = (u16*)ws;   ws += (size_t)Dq * Dq * 2;          // 1.2 MB
    u16* Whhb  = (u16*)ws;   ws += (size_t)Dq * Dq * 2;          // 1.2 MB
    u16* Vpad  = (u16*)ws;   ws += (size_t)(Mq + Bq) * Dq * 2;   // 25.2 MB
    u16* Gpad  = (u16*)ws;   ws += (size_t)(Mq + Bq) * Dq * 2;   // 25.2 MB
    u16* Eout  = (u16*)ws;   ws += (size_t)Mq * Dq * 2;          // 25.2 MB

    prep_kernel<<<dim3((Dq * Dq + 255) / 256), 256, 0, stream>>>(
        Wih, Whh, Wihb, Whhb, Vpad, Gpad);
    transpose_kernel<<<dim3(Lq / 64, Dq / 64, Bq), 256, 0, stream>>>(x, Xt);

    dim3 ggrid(Mq / 128, Dq / 128);   // (128, 6): m fast (distinct A rows per XCD wave)
    // pass A: V = relu(X@Wih^T + b)
    gemm_kernel<1, 0><<<ggrid, 256, 0, stream>>>(Xt, Wihb, nullptr, nullptr, Vpad, bih, bhh);
    // pass B: G = relu(X@Wih^T + Vprev@Whh^T + b)   (Vprev via +4-row pad)
    gemm_kernel<2, 0><<<ggrid, 256, 0, stream>>>(Xt, Wihb, Vpad, Whhb, Gpad, bih, bhh);
    // pass C: E = relu(X@Wih^T + Gprev@Whh^T + b), stored transposed [B,D,L] bf16
    gemm_kernel<2, 1><<<ggrid, 256, 0, stream>>>(Xt, Wihb, Gpad, Whhb, Eout, bih, bhh);

    ln_kernel<<<dim3(Bq * Dq), 256, 0, stream>>>(Eout, x, gamma, beta, out);
}

// Round 3
// 262.308 us; speedup vs baseline: 1.0949x; 1.0489x over previous
//
#include <hip/hip_runtime.h>

typedef unsigned short u16;
typedef __bf16 bf16x8 __attribute__((ext_vector_type(8)));
typedef float f32x4 __attribute__((ext_vector_type(4)));
typedef unsigned short u16x8 __attribute__((ext_vector_type(8)));

#define Bq 4
#define Dq 768
#define Lq 4096
#define Mq (Lq * Bq)   // 16384

__device__ __forceinline__ u16 f2bf(float f) {
    unsigned int u = __builtin_bit_cast(unsigned int, f);
    u += 0x7fffu + ((u >> 16) & 1u);   // RNE
    return (u16)(u >> 16);
}

__device__ __forceinline__ float bf2f(u16 h) {
    return __builtin_bit_cast(float, (unsigned int)h << 16);
}

__device__ __forceinline__ void async16(const void* g, void* l) {
    __builtin_amdgcn_global_load_lds(
        (const __attribute__((address_space(1))) unsigned int*)(unsigned long long)g,
        (__attribute__((address_space(3))) unsigned int*)(unsigned int)(unsigned long long)l,
        16, 0, 0);
}

// ---- prep: fp32 weights -> bf16, zero the 4 pad rows of Vpad/Gpad ----
__global__ __launch_bounds__(256) void prep_kernel(
    const float* __restrict__ Wih, const float* __restrict__ Whh,
    u16* __restrict__ Wihb, u16* __restrict__ Whhb,
    u16* __restrict__ Vpad, u16* __restrict__ Gpad) {
    int i = blockIdx.x * 256 + threadIdx.x;
    if (i < Dq * Dq) {
        Wihb[i] = f2bf(Wih[i]);
        Whhb[i] = f2bf(Whh[i]);
    }
    if (i < Bq * Dq) { Vpad[i] = 0; Gpad[i] = 0; }
}

// ---- transpose x [B,D,L] fp32 -> Xt [(l*B+b), d] bf16 ----
__global__ __launch_bounds__(256) void transpose_kernel(
    const float* __restrict__ x, u16* __restrict__ Xt) {
    __shared__ u16 tile[64][66];
    int b = blockIdx.z, d0 = blockIdx.y * 64, l0 = blockIdx.x * 64;
    int tx = threadIdx.x & 63, ty = threadIdx.x >> 6;
    const float* xp = x + ((size_t)b * Dq + d0) * Lq + l0;
#pragma unroll
    for (int i = 0; i < 16; ++i) {
        int r = i * 4 + ty;
        tile[r][tx] = f2bf(xp[(size_t)r * Lq + tx]);
    }
    __syncthreads();
    u16* xt = Xt + ((size_t)l0 * Bq + b) * Dq + d0;
#pragma unroll
    for (int i = 0; i < 16; ++i) {
        int c = i * 4 + ty;
        xt[(size_t)c * Bq * Dq + tx] = tile[tx][c];
    }
}

// ---- GEMM with software-pipelined (double-buffered) staging ----
// C[m,n] = sum_seg sum_k Aseg[m,k]*Wseg[n,k], then relu(+b_ih+b_hh)
// MODE 0: bf16 Out at rows +4 (l-shift via pad), written via LDS repack
// MODE 1: bf16 Out transposed to [B,D,L] via LDS
// K-loop: iter j computes from buf[j&1] while prefetching j+1 into buf[~j&1].
// Raw asm barriers keep the compiler from draining vmcnt(0): the start-of-iter
// wait is vmcnt(8) = "the 8 loads issued one full iteration ago are done".
template <int NSEG, int MODE>
__global__ __launch_bounds__(256) void gemm_kernel(
    const u16* __restrict__ A0, const u16* __restrict__ W0,
    const u16* __restrict__ A1, const u16* __restrict__ W1,
    u16* __restrict__ Out,
    const float* __restrict__ bih, const float* __restrict__ bhh) {
    extern __shared__ __align__(16) char smem[];   // 2 x 32 KB buffers
    const int NK = 12 * NSEG;

    int tid = threadIdx.x;
    int wave = tid >> 6, lane = tid & 63;
    int wr = wave >> 1, wc = wave & 1;
    int m0 = blockIdx.x * 128, n0 = blockIdx.y * 128;
    int lr = lane & 15, lq = lane >> 4;

    // staging: wave w stages rows [w*32, w*32+32); lane -> (row=lane>>2, seg=lane&3)
    // => LDS offset == uniform base + lane*16B (global_load_lds requirement)
    size_t aoff = (size_t)(m0 + wave * 32 + (lane >> 2)) * Dq + (lane & 3) * 8;
    size_t boff = (size_t)(n0 + wave * 32 + (lane >> 2)) * Dq + (lane & 3) * 8;
    int ro = (wave * 32) * 32;   // u16 offset of wave's staging region

    auto stage = [&](int j, char* buf) {
        const u16* Ab = A0; const u16* Wb = W0; int kk = j;
        if (NSEG == 2 && j >= 12) { Ab = A1; Wb = W1; kk = j - 12; }
        const u16* ga = Ab + aoff + kk * 64;
        const u16* gb = Wb + boff + kk * 64;
        u16* s0 = (u16*)buf;
        async16(ga,                s0 + ro);
        async16(ga + 16 * Dq,      s0 + ro + 512);
        async16(ga + 32,           s0 + 4096 + ro);
        async16(ga + 16 * Dq + 32, s0 + 4096 + ro + 512);
        async16(gb,                s0 + 8192 + ro);
        async16(gb + 16 * Dq,      s0 + 8192 + ro + 512);
        async16(gb + 32,           s0 + 12288 + ro);
        async16(gb + 16 * Dq + 32, s0 + 12288 + ro + 512);
    };

    f32x4 acc[4][4];
#pragma unroll
    for (int i = 0; i < 4; ++i)
#pragma unroll
        for (int j = 0; j < 4; ++j) acc[i][j] = f32x4{0.f, 0.f, 0.f, 0.f};

    stage(0, smem);   // 8 outstanding
    for (int j = 0; j < NK; ++j) {
        char* cur = smem + (size_t)(j & 1) * 32768;
        if (j + 1 < NK) {
            stage(j + 1, smem + (size_t)((j + 1) & 1) * 32768);  // 16 outstanding
            // wait only for iter j's loads (issued one iteration ago)
            asm volatile("s_waitcnt vmcnt(8)\n\ts_barrier" ::: "memory");
        } else {
            asm volatile("s_waitcnt vmcnt(0)\n\ts_barrier" ::: "memory");
        }

        const u16* As = (const u16*)cur;
#pragma unroll
        for (int s = 0; s < 2; ++s) {
            const u16* Asub = As + s * 4096;
            const u16* Bsub = As + 8192 + s * 4096;
            bf16x8 af[4], bfr[4];
#pragma unroll
            for (int mt = 0; mt < 4; ++mt)
                af[mt] = *(const bf16x8*)(Asub + (wr * 64 + mt * 16 + lr) * 32 + lq * 8);
#pragma unroll
            for (int nt = 0; nt < 4; ++nt)
                bfr[nt] = *(const bf16x8*)(Bsub + (wc * 64 + nt * 16 + lr) * 32 + lq * 8);
#pragma unroll
            for (int mt = 0; mt < 4; ++mt)
#pragma unroll
                for (int nt = 0; nt < 4; ++nt)
                    acc[mt][nt] = __builtin_amdgcn_mfma_f32_16x16x32_bf16(
                        af[mt], bfr[nt], acc[mt][nt], 0, 0, 0);
        }
        // all this wave's ds_read data has landed (lgkm) before signaling, so
        // next iteration's prefetch can't overwrite a buffer still being read
        asm volatile("s_waitcnt lgkmcnt(0)\n\ts_barrier" ::: "memory");
    }

    // ---- epilogue ----  C/D layout: col = lane&15, row = (lane>>4)*4 + r
    if constexpr (MODE == 0) {
        // repack 128x128 bf16 tile via LDS (rows padded to 136 u16 = 17x16B)
        u16* tb = (u16*)smem;
#pragma unroll
        for (int nt = 0; nt < 4; ++nt) {
            int cl = wc * 64 + nt * 16 + lr;
            float bsum = bih[n0 + cl] + bhh[n0 + cl];
#pragma unroll
            for (int mt = 0; mt < 4; ++mt) {
                int rl = wr * 64 + mt * 16 + lq * 4;
                f32x4 v = acc[mt][nt];
#pragma unroll
                for (int r = 0; r < 4; ++r)
                    tb[(rl + r) * 136 + cl] = f2bf(fmaxf(v[r] + bsum, 0.f));
            }
        }
        __syncthreads();
        int rlane = tid & 15, rrow = tid >> 4;
#pragma unroll
        for (int s = 0; s < 8; ++s) {
            int row = s * 16 + rrow;
            u16x8 hv = *(const u16x8*)(tb + row * 136 + rlane * 8);
            *(u16x8*)(Out + (size_t)(m0 + row + Bq) * Dq + n0 + rlane * 8) = hv;
        }
    } else {
        // transpose through LDS so [B,D,L] writes are contiguous in l
        float* ep = (float*)smem;
        float* epw = ep + wave * (64 * 17);
        int l0w = (m0 >> 2) + wr * 16;   // wave covers 16 l values, 4 b values
#pragma unroll
        for (int nt = 0; nt < 4; ++nt) {
            int gn = n0 + wc * 64 + nt * 16 + lr;
            float bsum = bih[gn] + bhh[gn];
#pragma unroll
            for (int mt = 0; mt < 4; ++mt) {
                int lmb = mt * 16 + lq * 4;
                f32x4 v = acc[mt][nt];
#pragma unroll
                for (int r = 0; r < 4; ++r)
                    epw[(lmb + r) * 17 + lr] = fmaxf(v[r] + bsum, 0.f);
            }
            __syncthreads();
            int bb = lane >> 4, cc = lane & 15;
            int gnc = n0 + wc * 64 + nt * 16 + cc;
            float vals[16];
#pragma unroll
            for (int ll = 0; ll < 16; ++ll)
                vals[ll] = epw[(ll * 4 + bb) * 17 + cc];
            u16* dst = Out + (size_t)bb * (Dq * Lq) + (size_t)gnc * Lq + l0w;
            u16x8 h0, h1;
#pragma unroll
            for (int k = 0; k < 8; ++k) { h0[k] = f2bf(vals[k]); h1[k] = f2bf(vals[8 + k]); }
            *(u16x8*)dst = h0;
            *(u16x8*)(dst + 8) = h1;
            __syncthreads();
        }
    }
}

// ---- fused residual + LayerNorm over L (E is bf16 [B,D,L]) ----
__global__ __launch_bounds__(256) void ln_kernel(
    const u16* __restrict__ E, const float* __restrict__ x,
    const float* __restrict__ gamma, const float* __restrict__ beta,
    float* __restrict__ out) {
    __shared__ float red[2][4];
    size_t row = blockIdx.x;
    const u16x8* e8 = (const u16x8*)(E + row * Lq);
    const float* xr = x + row * Lq;
    float* o = out + row * Lq;
    int t = threadIdx.x;
    float z[16];
    float s = 0.f, sq = 0.f;
#pragma unroll
    for (int i = 0; i < 2; ++i) {
        int c = i * 256 + t;
        u16x8 ev = e8[c];
        f32x4 xv0 = *(const f32x4*)(xr + c * 8);
        f32x4 xv1 = *(const f32x4*)(xr + c * 8 + 4);
#pragma unroll
        for (int j = 0; j < 4; ++j) {
            float z0 = bf2f(ev[j]) + xv0[j];
            float z1 = bf2f(ev[4 + j]) + xv1[j];
            z[i * 8 + j] = z0;
            z[i * 8 + 4 + j] = z1;
            s += z0 + z1;
            sq += z0 * z0 + z1 * z1;
        }
    }
#pragma unroll
    for (int off = 32; off > 0; off >>= 1) {
        s += __shfl_down(s, off);
        sq += __shfl_down(sq, off);
    }
    int wave = t >> 6, lane = t & 63;
    if (lane == 0) { red[0][wave] = s; red[1][wave] = sq; }
    __syncthreads();
    s = red[0][0] + red[0][1] + red[0][2] + red[0][3];
    sq = red[1][0] + red[1][1] + red[1][2] + red[1][3];
    float mean = s * (1.f / Lq);
    float var = sq * (1.f / Lq) - mean * mean;
    float rstd = rsqrtf(var + 1e-12f);
#pragma unroll
    for (int i = 0; i < 2; ++i) {
        int c = i * 256 + t;
#pragma unroll
        for (int h = 0; h < 2; ++h) {
            int idx = c * 8 + h * 4;
            f32x4 gv = *(const f32x4*)(gamma + idx);
            f32x4 bv = *(const f32x4*)(beta + idx);
            f32x4 ov;
#pragma unroll
            for (int j = 0; j < 4; ++j)
                ov[j] = (z[i * 8 + h * 4 + j] - mean) * rstd * gv[j] + bv[j];
            *(f32x4*)(o + idx) = ov;
        }
    }
}

extern "C" void kernel_launch(void* const* d_in, const int* in_sizes, int n_in,
                              void* d_out, int out_size, void* d_ws, size_t ws_size,
                              hipStream_t stream) {
    const float* x     = (const float*)d_in[0];
    const float* Wih   = (const float*)d_in[1];
    const float* Whh   = (const float*)d_in[2];
    const float* bih   = (const float*)d_in[3];
    const float* bhh   = (const float*)d_in[4];
    const float* gamma = (const float*)d_in[5];
    const float* beta  = (const float*)d_in[6];
    float* out = (float*)d_out;

    char* ws = (char*)d_ws;
    u16* Xt    = (u16*)ws;   ws += (size_t)Mq * Dq * 2;
    u16* Wihb  = (u16*)ws;   ws += (size_t)Dq * Dq * 2;
    u16* Whhb  = (u16*)ws;   ws += (size_t)Dq * Dq * 2;
    u16* Vpad  = (u16*)ws;   ws += (size_t)(Mq + Bq) * Dq * 2;
    u16* Gpad  = (u16*)ws;   ws += (size_t)(Mq + Bq) * Dq * 2;
    u16* Eout  = (u16*)ws;   ws += (size_t)Mq * Dq * 2;

    prep_kernel<<<dim3((Dq * Dq + 255) / 256), 256, 0, stream>>>(
        Wih, Whh, Wihb, Whhb, Vpad, Gpad);
    transpose_kernel<<<dim3(Lq / 64, Dq / 64, Bq), 256, 0, stream>>>(x, Xt);

    dim3 ggrid(Mq / 128, Dq / 128);   // (128, 6)
    gemm_kernel<1, 0><<<ggrid, 256, 65536, stream>>>(Xt, Wihb, nullptr, nullptr, Vpad, bih, bhh);
    gemm_kernel<2, 0><<<ggrid, 256, 65536, stream>>>(Xt, Wihb, Vpad, Whhb, Gpad, bih, bhh);
    gemm_kernel<2, 1><<<ggrid, 256, 65536, stream>>>(Xt, Wihb, Gpad, Whhb, Eout, bih, bhh);

    ln_kernel<<<dim3(Bq * Dq), 256, 0, stream>>>(Eout, x, gamma, beta, out);
}

// Round 4
// 232.195 us; speedup vs baseline: 1.2369x; 1.1297x over previous
//
#include <hip/hip_runtime.h>

typedef unsigned short u16;
typedef __bf16 bf16x8 __attribute__((ext_vector_type(8)));
typedef float f32x4 __attribute__((ext_vector_type(4)));
typedef unsigned short u16x8 __attribute__((ext_vector_type(8)));

#define Bq 4
#define Dq 768
#define Lq 4096
#define Mq (Lq * Bq)   // 16384
#define NK 24          // K=768 / BK=32

__device__ __forceinline__ u16 f2bf(float f) {
    unsigned int u = __builtin_bit_cast(unsigned int, f);
    u += 0x7fffu + ((u >> 16) & 1u);   // RNE
    return (u16)(u >> 16);
}

__device__ __forceinline__ float bf2f(u16 h) {
    return __builtin_bit_cast(float, (unsigned int)h << 16);
}

__device__ __forceinline__ void async16(const void* g, void* l) {
    __builtin_amdgcn_global_load_lds(
        (const __attribute__((address_space(1))) unsigned int*)(unsigned long long)g,
        (__attribute__((address_space(3))) unsigned int*)(unsigned int)(unsigned long long)l,
        16, 0, 0);
}

// ---- prep: fp32 weights -> bf16, zero the 4 pad rows of Vpad/Gpad ----
__global__ __launch_bounds__(256) void prep_kernel(
    const float* __restrict__ Wih, const float* __restrict__ Whh,
    u16* __restrict__ Wihb, u16* __restrict__ Whhb,
    u16* __restrict__ Vpad, u16* __restrict__ Gpad) {
    int i = blockIdx.x * 256 + threadIdx.x;
    if (i < Dq * Dq) {
        Wihb[i] = f2bf(Wih[i]);
        Whhb[i] = f2bf(Whh[i]);
    }
    if (i < Bq * Dq) { Vpad[i] = 0; Gpad[i] = 0; }
}

// ---- transpose x [B,D,L] fp32 -> Xt [(l*B+b), d] bf16 ----
__global__ __launch_bounds__(256) void transpose_kernel(
    const float* __restrict__ x, u16* __restrict__ Xt) {
    __shared__ u16 tile[64][66];
    int b = blockIdx.z, d0 = blockIdx.y * 64, l0 = blockIdx.x * 64;
    int tx = threadIdx.x & 63, ty = threadIdx.x >> 6;
    const float* xp = x + ((size_t)b * Dq + d0) * Lq + l0;
#pragma unroll
    for (int i = 0; i < 16; ++i) {
        int r = i * 4 + ty;
        tile[r][tx] = f2bf(xp[(size_t)r * Lq + tx]);
    }
    __syncthreads();
    u16* xt = Xt + ((size_t)l0 * Bq + b) * Dq + d0;
#pragma unroll
    for (int i = 0; i < 16; ++i) {
        int c = i * 4 + ty;
        xt[(size_t)c * Bq * Dq + tx] = tile[tx][c];
    }
}

// ---- K=768 GEMM, BK=32, 3-deep software pipeline (48 KB LDS) ----
// acc = A@W^T  (A row-major [M][768] bf16, W [N][768] bf16, tile 128x128)
// MODE 0 (pass A): Ub = acc + bih + bhh (bf16, natural rows); Vpad = relu(Ub) at +4
// MODE 1 (pass B): Gpad = relu(Ub + acc) at +4 rows
// MODE 2 (pass C): Eout[B,D,L] = relu(Ub + acc), transposed via LDS, bf16
template <int MODE>
__global__ __launch_bounds__(256) void gemm_kernel(
    const u16* __restrict__ A, const u16* __restrict__ W,
    const u16* __restrict__ Ub_in, u16* __restrict__ Out0, u16* __restrict__ Out1,
    const float* __restrict__ bih, const float* __restrict__ bhh) {
    __shared__ __align__(16) char smem[49152];   // 3 x (8KB A + 8KB B)

    int tid = threadIdx.x;
    int wave = tid >> 6, lane = tid & 63;
    int wr = wave >> 1, wc = wave & 1;
    int m0 = blockIdx.x * 128, n0 = blockIdx.y * 128;
    int lr = lane & 15, lq = lane >> 4;

    // staging: wave w covers rows [w*32, w*32+32); per async16 lane -> (row=lane>>2,
    // seg=lane&3) so LDS dst == uniform base + lane*16B (HW requirement)
    const u16* ga = A + (size_t)(m0 + wave * 32 + (lane >> 2)) * Dq + (lane & 3) * 8;
    const u16* gb = W + (size_t)(n0 + wave * 32 + (lane >> 2)) * Dq + (lane & 3) * 8;
    int ro = wave * 1024;   // u16 offset of wave's 32-row staging chunk

    u16* b0 = (u16*)smem;
    u16* b1 = b0 + 8192;
    u16* b2 = b0 + 16384;

    auto stage = [&](u16* bs) {
        async16(ga,           bs + ro);
        async16(ga + 16 * Dq, bs + ro + 512);
        async16(gb,           bs + 4096 + ro);
        async16(gb + 16 * Dq, bs + 4096 + ro + 512);
        ga += 32; gb += 32;
    };

    f32x4 acc[4][4];
#pragma unroll
    for (int i = 0; i < 4; ++i)
#pragma unroll
        for (int j = 0; j < 4; ++j) acc[i][j] = f32x4{0.f, 0.f, 0.f, 0.f};

    stage(b0);
    stage(b1);          // 8 loads outstanding
    u16 *cur = b0, *nxt = b1, *pre = b2;

    for (int j = 0; j < NK; ++j) {
        // wait for iter j's 4 loads (exactly one later stage, 4 loads, may remain)
        if (j < NK - 1)
            asm volatile("s_waitcnt vmcnt(4)\n\ts_barrier" ::: "memory");
        else
            asm volatile("s_waitcnt vmcnt(0)\n\ts_barrier" ::: "memory");
        if (j < NK - 2) stage(pre);   // prefetch j+2 (2-iteration lead)

        const u16* As = cur;
        const u16* Bs = cur + 4096;
        bf16x8 af[4], bfr[4];
#pragma unroll
        for (int mt = 0; mt < 4; ++mt)
            af[mt] = *(const bf16x8*)(As + (wr * 64 + mt * 16 + lr) * 32 + lq * 8);
#pragma unroll
        for (int nt = 0; nt < 4; ++nt)
            bfr[nt] = *(const bf16x8*)(Bs + (wc * 64 + nt * 16 + lr) * 32 + lq * 8);
#pragma unroll
        for (int mt = 0; mt < 4; ++mt)
#pragma unroll
            for (int nt = 0; nt < 4; ++nt)
                acc[mt][nt] = __builtin_amdgcn_mfma_f32_16x16x32_bf16(
                    af[mt], bfr[nt], acc[mt][nt], 0, 0, 0);

        u16* t = cur; cur = nxt; nxt = pre; pre = t;
    }
    __syncthreads();   // full drain before epilogue smem reuse

    // ---- epilogue ----  C/D layout: col = lane&15, row = (lane>>4)*4 + r
    u16* tb = (u16*)smem;                 // [128][136] bf16 tile (34.8 KB)
    int rlane = tid & 15, rrow = tid >> 4;

    if constexpr (MODE == 0) {
#pragma unroll
        for (int nt = 0; nt < 4; ++nt) {
            int cl = wc * 64 + nt * 16 + lr;
            float bsum = bih[n0 + cl] + bhh[n0 + cl];
#pragma unroll
            for (int mt = 0; mt < 4; ++mt) {
                int rl = wr * 64 + mt * 16 + lq * 4;
                f32x4 v = acc[mt][nt];
#pragma unroll
                for (int r = 0; r < 4; ++r)
                    tb[(rl + r) * 136 + cl] = f2bf(v[r] + bsum);
            }
        }
        __syncthreads();
#pragma unroll
        for (int s = 0; s < 8; ++s) {
            int row = s * 16 + rrow;
            u16x8 hv = *(const u16x8*)(tb + row * 136 + rlane * 8);
            *(u16x8*)(Out0 + (size_t)(m0 + row) * Dq + n0 + rlane * 8) = hv;   // Ub
            u16x8 hr;
#pragma unroll
            for (int k = 0; k < 8; ++k) hr[k] = (hv[k] & 0x8000u) ? (u16)0 : hv[k];
            *(u16x8*)(Out1 + (size_t)(m0 + row + Bq) * Dq + n0 + rlane * 8) = hr; // Vpad
        }
    } else if constexpr (MODE == 1) {
        // load Ub tile into LDS (coalesced), add+relu in acc-domain, repack-store
#pragma unroll
        for (int s = 0; s < 8; ++s) {
            int row = s * 16 + rrow;
            *(u16x8*)(tb + row * 136 + rlane * 8) =
                *(const u16x8*)(Ub_in + (size_t)(m0 + row) * Dq + n0 + rlane * 8);
        }
        __syncthreads();
#pragma unroll
        for (int nt = 0; nt < 4; ++nt) {
            int cl = wc * 64 + nt * 16 + lr;
#pragma unroll
            for (int mt = 0; mt < 4; ++mt) {
                int rl = wr * 64 + mt * 16 + lq * 4;
                f32x4 v = acc[mt][nt];
#pragma unroll
                for (int r = 0; r < 4; ++r) {
                    float g = fmaxf(v[r] + bf2f(tb[(rl + r) * 136 + cl]), 0.f);
                    tb[(rl + r) * 136 + cl] = f2bf(g);   // cell owned by this thread
                }
            }
        }
        __syncthreads();
#pragma unroll
        for (int s = 0; s < 8; ++s) {
            int row = s * 16 + rrow;
            u16x8 hv = *(const u16x8*)(tb + row * 136 + rlane * 8);
            *(u16x8*)(Out0 + (size_t)(m0 + row + Bq) * Dq + n0 + rlane * 8) = hv; // Gpad
        }
    } else {
        // MODE 2: fold Ub into acc, then transpose to [B,D,L] bf16 via LDS
#pragma unroll
        for (int s = 0; s < 8; ++s) {
            int row = s * 16 + rrow;
            *(u16x8*)(tb + row * 136 + rlane * 8) =
                *(const u16x8*)(Ub_in + (size_t)(m0 + row) * Dq + n0 + rlane * 8);
        }
        __syncthreads();
#pragma unroll
        for (int nt = 0; nt < 4; ++nt) {
            int cl = wc * 64 + nt * 16 + lr;
#pragma unroll
            for (int mt = 0; mt < 4; ++mt) {
                int rl = wr * 64 + mt * 16 + lq * 4;
#pragma unroll
                for (int r = 0; r < 4; ++r)
                    acc[mt][nt][r] = fmaxf(acc[mt][nt][r] + bf2f(tb[(rl + r) * 136 + cl]), 0.f);
            }
        }
        __syncthreads();
        float* ep = (float*)smem;
        float* epw = ep + wave * (64 * 17);
        int l0w = (m0 >> 2) + wr * 16;   // wave covers 16 l values, 4 b values
#pragma unroll
        for (int nt = 0; nt < 4; ++nt) {
#pragma unroll
            for (int mt = 0; mt < 4; ++mt) {
                int lmb = mt * 16 + lq * 4;
                f32x4 v = acc[mt][nt];
#pragma unroll
                for (int r = 0; r < 4; ++r)
                    epw[(lmb + r) * 17 + lr] = v[r];
            }
            __syncthreads();
            int bb = lane >> 4, cc = lane & 15;
            int gnc = n0 + wc * 64 + nt * 16 + cc;
            float vals[16];
#pragma unroll
            for (int ll = 0; ll < 16; ++ll)
                vals[ll] = epw[(ll * 4 + bb) * 17 + cc];
            u16* dst = Out0 + (size_t)bb * (Dq * Lq) + (size_t)gnc * Lq + l0w;
            u16x8 h0, h1;
#pragma unroll
            for (int k = 0; k < 8; ++k) { h0[k] = f2bf(vals[k]); h1[k] = f2bf(vals[8 + k]); }
            *(u16x8*)dst = h0;
            *(u16x8*)(dst + 8) = h1;
            __syncthreads();
        }
    }
}

// ---- fused residual + LayerNorm over L (E is bf16 [B,D,L]) ----
__global__ __launch_bounds__(256) void ln_kernel(
    const u16* __restrict__ E, const float* __restrict__ x,
    const float* __restrict__ gamma, const float* __restrict__ beta,
    float* __restrict__ out) {
    __shared__ float red[2][4];
    size_t row = blockIdx.x;
    const u16x8* e8 = (const u16x8*)(E + row * Lq);
    const float* xr = x + row * Lq;
    float* o = out + row * Lq;
    int t = threadIdx.x;
    float z[16];
    float s = 0.f, sq = 0.f;
#pragma unroll
    for (int i = 0; i < 2; ++i) {
        int c = i * 256 + t;
        u16x8 ev = e8[c];
        f32x4 xv0 = *(const f32x4*)(xr + c * 8);
        f32x4 xv1 = *(const f32x4*)(xr + c * 8 + 4);
#pragma unroll
        for (int j = 0; j < 4; ++j) {
            float z0 = bf2f(ev[j]) + xv0[j];
            float z1 = bf2f(ev[4 + j]) + xv1[j];
            z[i * 8 + j] = z0;
            z[i * 8 + 4 + j] = z1;
            s += z0 + z1;
            sq += z0 * z0 + z1 * z1;
        }
    }
#pragma unroll
    for (int off = 32; off > 0; off >>= 1) {
        s += __shfl_down(s, off);
        sq += __shfl_down(sq, off);
    }
    int wave = t >> 6, lane = t & 63;
    if (lane == 0) { red[0][wave] = s; red[1][wave] = sq; }
    __syncthreads();
    s = red[0][0] + red[0][1] + red[0][2] + red[0][3];
    sq = red[1][0] + red[1][1] + red[1][2] + red[1][3];
    float mean = s * (1.f / Lq);
    float var = sq * (1.f / Lq) - mean * mean;
    float rstd = rsqrtf(var + 1e-12f);
#pragma unroll
    for (int i = 0; i < 2; ++i) {
        int c = i * 256 + t;
#pragma unroll
        for (int h = 0; h < 2; ++h) {
            int idx = c * 8 + h * 4;
            f32x4 gv = *(const f32x4*)(gamma + idx);
            f32x4 bv = *(const f32x4*)(beta + idx);
            f32x4 ov;
#pragma unroll
            for (int j = 0; j < 4; ++j)
                ov[j] = (z[i * 8 + h * 4 + j] - mean) * rstd * gv[j] + bv[j];
            *(f32x4*)(o + idx) = ov;
        }
    }
}

extern "C" void kernel_launch(void* const* d_in, const int* in_sizes, int n_in,
                              void* d_out, int out_size, void* d_ws, size_t ws_size,
                              hipStream_t stream) {
    const float* x     = (const float*)d_in[0];
    const float* Wih   = (const float*)d_in[1];
    const float* Whh   = (const float*)d_in[2];
    const float* bih   = (const float*)d_in[3];
    const float* bhh   = (const float*)d_in[4];
    const float* gamma = (const float*)d_in[5];
    const float* beta  = (const float*)d_in[6];
    float* out = (float*)d_out;

    char* ws = (char*)d_ws;
    u16* Xt    = (u16*)ws;   ws += (size_t)Mq * Dq * 2;          // 25.2 MB
    u16* Wihb  = (u16*)ws;   ws += (size_t)Dq * Dq * 2;
    u16* Whhb  = (u16*)ws;   ws += (size_t)Dq * Dq * 2;
    u16* Ub    = (u16*)ws;   ws += (size_t)Mq * Dq * 2;          // 25.2 MB
    u16* Vpad  = (u16*)ws;   ws += (size_t)(Mq + Bq) * Dq * 2;   // 25.2 MB
    u16* Gpad  = (u16*)ws;   ws += (size_t)(Mq + Bq) * Dq * 2;   // 25.2 MB
    u16* Eout  = (u16*)ws;   ws += (size_t)Mq * Dq * 2;          // 25.2 MB

    prep_kernel<<<dim3((Dq * Dq + 255) / 256), 256, 0, stream>>>(
        Wih, Whh, Wihb, Whhb, Vpad, Gpad);
    transpose_kernel<<<dim3(Lq / 64, Dq / 64, Bq), 256, 0, stream>>>(x, Xt);

    dim3 ggrid(Mq / 128, Dq / 128);   // (128, 6) = 768 blocks = 3/CU, one round
    // pass A: Ub = X@Wih^T + bih + bhh ; Vpad = relu(Ub) shifted +4 rows
    gemm_kernel<0><<<ggrid, 256, 0, stream>>>(Xt,   Wihb, nullptr, Ub,  Vpad, bih, bhh);
    // pass B: Gpad = relu(Ub + Vprev@Whh^T) shifted +4 rows
    gemm_kernel<1><<<ggrid, 256, 0, stream>>>(Vpad, Whhb, Ub, Gpad, nullptr, bih, bhh);
    // pass C: Eout[B,D,L] = relu(Ub + Gprev@Whh^T), transposed, bf16
    gemm_kernel<2><<<ggrid, 256, 0, stream>>>(Gpad, Whhb, Ub, Eout, nullptr, bih, bhh);

    ln_kernel<<<dim3(Bq * Dq), 256, 0, stream>>>(Eout, x, gamma, beta, out);
}